// Round 2
// baseline (121.564 us; speedup 1.0000x reference)
//
#include <hip/hip_runtime.h>

// Problem constants (fixed by reference setup_inputs)
constexpr int B  = 32;
constexpr int S  = 32;
constexpr int W  = 30;
constexpr int E  = 300;
constexpr int EV = E / 4;            // 75 float4 per embedding row (1200 B, 16B-aligned)
constexpr int NSENT = B * S;         // 1024 sentences
constexpr int NTOK  = NSENT * W;     // 30720 tokens
constexpr int NF4   = NTOK * EV;     // 2,304,000 float4 outputs per embedding tensor

// Output layout in d_out (flat f32, reference return order):
constexpr long OFF_EMB   = 0;                                  // [1024,30,300]
constexpr long OFF_SHARE = (long)NTOK * E;                     // 9,216,000  [32,960,300] (same flat order)
constexpr long OFF_MASK  = OFF_SHARE + (long)NTOK * E;         // 18,432,000 [32,960]
constexpr long OFF_WM    = OFF_MASK + (long)NTOK;              // 18,462,720 [1024,30]
constexpr long OFF_SM    = OFF_WM + (long)NTOK;                // 18,493,440 [32,32]

// ---------------------------------------------------------------------------
// Prep: one thread per sentence. Computes first-zero position z, writes all
// three masks, stores z to workspace for the gather kernel.
// ---------------------------------------------------------------------------
__global__ __launch_bounds__(256) void prep_kernel(
    const int* __restrict__ input,   // [30720]
    float* __restrict__ out,
    int* __restrict__ zarr)          // [1024] in workspace
{
    const int sent = blockIdx.x * 256 + threadIdx.x;
    if (sent >= NSENT) return;

    int vals[W];
    #pragma unroll
    for (int k = 0; k < W; ++k) vals[k] = input[sent * W + k];

    int z = W, any = 0;
    #pragma unroll
    for (int k = 0; k < W; ++k) {
        any |= (vals[k] != 0);
        if (vals[k] == 0 && z == W) z = k;
    }

    zarr[sent] = z;
    out[OFF_SM + sent] = any ? 1.0f : 0.0f;

    #pragma unroll
    for (int k = 0; k < W; ++k) {
        out[OFF_WM   + (long)sent * W + k] = (vals[k] != 0) ? 1.0f : 0.0f;
        // temp[k] = vals[k] for k < z else 0; k < z implies vals[k] != 0
        out[OFF_MASK + (long)sent * W + k] = (k < z) ? 1.0f : 0.0f;
    }
}

// ---------------------------------------------------------------------------
// Gather: one thread per float4 of the embedding row. No LDS, no barriers —
// pure TLP. 9000 blocks x 256 threads = 2,304,000 threads, each does two
// independent gather loads + two coalesced float4 stores.
// ---------------------------------------------------------------------------
__global__ __launch_bounds__(256) void gather_kernel(
    const int* __restrict__ input,
    const int* __restrict__ zarr,
    const float* __restrict__ Wemb,
    float* __restrict__ out)
{
    const int g = blockIdx.x * 256 + threadIdx.x;   // 0 .. NF4-1

    const int token = g / EV;            // 0..30719 (magic-mul)
    const int q     = g - token * EV;    // float4 within row
    const int sent  = token / W;
    const int k     = token - sent * W;

    const int idx = input[token];        // L1/L2 broadcast (75 threads share)
    const int z   = zarr[sent];          // tiny, fully cached
    const int tix = (k < z) ? idx : 0;   // cumprod-keep semantics

    const float4* __restrict__ W4 = (const float4*)Wemb;
    float4 a = W4[(long)idx * EV + q];
    float4 b = (tix == idx) ? a : W4[(long)q];   // tix!=idx ⇒ tix==0

    ((float4*)(out + OFF_EMB))[g]   = a;
    ((float4*)(out + OFF_SHARE))[g] = b;
}

extern "C" void kernel_launch(void* const* d_in, const int* in_sizes, int n_in,
                              void* d_out, int out_size, void* d_ws, size_t ws_size,
                              hipStream_t stream) {
    const int*   input = (const int*)d_in[0];     // [32,32,30] token ids
    const float* Wemb  = (const float*)d_in[1];   // [50000,300]
    float*       out   = (float*)d_out;
    int*         zarr  = (int*)d_ws;              // 1024 ints of scratch

    prep_kernel<<<(NSENT + 255) / 256, 256, 0, stream>>>(input, out, zarr);
    gather_kernel<<<NF4 / 256, 256, 0, stream>>>(input, zarr, Wemb, out);
}

// Round 3
// 119.090 us; speedup vs baseline: 1.0208x; 1.0208x over previous
//
#include <hip/hip_runtime.h>

// Problem constants (fixed by reference setup_inputs)
constexpr int B  = 32;
constexpr int S  = 32;
constexpr int W  = 30;
constexpr int E  = 300;
constexpr int EV = E / 4;            // 75 float4 per embedding row (1200 B, 16B-aligned)
constexpr int NSENT = B * S;         // 1024 sentences
constexpr int NTOK  = NSENT * W;     // 30720 tokens
constexpr int PARTS = 9;             // blocks per sentence; 9*250 = 2250 = W*EV float4s
constexpr int F4_PER_PART = (W * EV) / PARTS;  // 250

// Output layout in d_out (flat f32, reference return order):
constexpr long OFF_EMB   = 0;                                  // [1024,30,300]
constexpr long OFF_SHARE = (long)NTOK * E;                     // 9,216,000  [32,960,300]
constexpr long OFF_MASK  = OFF_SHARE + (long)NTOK * E;         // 18,432,000 [32,960]
constexpr long OFF_WM    = OFF_MASK + (long)NTOK;              // 18,462,720 [1024,30]
constexpr long OFF_SM    = OFF_WM + (long)NTOK;                // 18,493,440 [32,32]

// ---------------------------------------------------------------------------
// Fully fused: grid = 9216 blocks (9 per sentence). Wave 0 computes the
// first-zero position via ballot+ctz (no serial scan), part-0 blocks write
// the three mask outputs; all blocks then gather 250 float4s of both
// embedding outputs. Single launch, single barrier.
// ---------------------------------------------------------------------------
__global__ __launch_bounds__(256) void fused_kernel(
    const int* __restrict__ input,      // [30720] token ids
    const float* __restrict__ Wemb,     // [50000*300]
    float* __restrict__ out)
{
    const int bid  = blockIdx.x;
    const int sent = bid / PARTS;
    const int part = bid - sent * PARTS;
    const int tid  = threadIdx.x;

    __shared__ int idx_s[W];
    __shared__ int tix_s[W];

    if (tid < 64) {
        const int k = tid;
        const int v = (k < W) ? input[sent * W + k] : 1;   // lanes >=30 -> nonzero
        const unsigned long long bz = __ballot(v == 0);    // bits >=30 are 0
        const int z = bz ? (int)__builtin_ctzll(bz) : W;   // first-zero position
        if (k < W) {
            idx_s[k] = v;
            tix_s[k] = (k < z) ? v : 0;                    // cumprod-keep
            if (part == 0) {
                out[OFF_WM   + (long)sent * W + k] = (v != 0) ? 1.0f : 0.0f;
                out[OFF_MASK + (long)sent * W + k] = (k < z) ? 1.0f : 0.0f;
            }
        }
        if (part == 0 && k == 0) {
            constexpr unsigned long long ALLZ = (1ull << W) - 1;
            out[OFF_SM + sent] = (bz != ALLZ) ? 1.0f : 0.0f;  // any nonzero
        }
    }
    __syncthreads();

    if (tid >= F4_PER_PART) return;

    const int i = part * F4_PER_PART + tid;   // 0..2249 within sentence
    const int k = i / EV;                     // word (const-div -> magic mul)
    const int q = i - k * EV;                 // float4 within row

    const int idx = idx_s[k];
    const int tix = tix_s[k];

    const float4* __restrict__ W4 = (const float4*)Wemb;
    const long g = (long)sent * (W * EV) + i;

    float4 a = W4[(long)idx * EV + q];
    float4 b = (tix == idx) ? a : W4[q];      // tix != idx  =>  tix == 0

    ((float4*)(out + OFF_EMB))[g]   = a;
    ((float4*)(out + OFF_SHARE))[g] = b;
}

extern "C" void kernel_launch(void* const* d_in, const int* in_sizes, int n_in,
                              void* d_out, int out_size, void* d_ws, size_t ws_size,
                              hipStream_t stream) {
    const int*   input = (const int*)d_in[0];     // [32,32,30] token ids
    const float* Wemb  = (const float*)d_in[1];   // [50000,300]
    float*       out   = (float*)d_out;

    fused_kernel<<<NSENT * PARTS, 256, 0, stream>>>(input, Wemb, out);
}